// Round 8
// baseline (200.730 us; speedup 1.0000x reference)
//
#include <hip/hip_runtime.h>

// GroupedConv2d via bf16 MFMA implicit GEMM — global weights + j-reuse-2.
// G=8 groups x 32 gathered channels -> J=64, 3x3 pad=1.
// x[16,256,56,56] fp32 -> out[16,512,56,56] fp32.
//
// (1) transpose_w: w[g][j][c][t] f32 -> wt[g][t][j][c] bf16 (295 KB in d_ws).
// (2) main: block = (g, b, chunk of 4 output rows). 4 waves = (j-half) x
// (row-half): each wave holds TWO j-tiles' A-fragments (A[2][9], 72 VGPR,
// loaded via 18 coalesced global_load_dwordx4 from wt) and computes 7
// pixel-tiles (its 2 rows) x 2 jt. Every LDS B-fragment feeds 2 MFMAs ->
// LDS reads/block halve vs round 6 (504 -> 252), which was the dominant
// per-CU pipe term (~25-40 us incl. read-side bank aliasing).
// LDS = quad-plane pixel buffer: [row 0..5][kq][px 0..58], 16 B/pixel-quad;
// px p holds input col p-1 (px 0/57 = zero halo).
//  * staging writes: 4x ds_write_b128, quad idx (4lr+3q+4p4+i) mod 8
//    sweeps all 8 quad-banks -> conflict-free.
//  * compute reads: per tile-pair 18 ds_read_b128 -> 36 MFMA in 4 indep
//    accumulator chains.
// 22.6 KB LDS, single __syncthreads, grid 1792 (7/CU); ~4 resident
// blocks/CU (VGPR-capped at launch_bounds(256,4)).
// (Round-7 run failed on container acquire — infra, same as round 3;
//  kernel re-audited clean, resubmitted unchanged.)

#define NG 8
#define CPER 32
#define CIN 256
#define NJ 64
#define NB 16
#define NH 56
#define NW 56
#define HW (NH * NW)
#define PLANE_DW 236            // 59 px * 4 dwords (16 B per pixel-quad)
#define SLOT_DW 944             // 4 planes per row-slot
#define NSLOT 6
#define BUF_DW (NSLOT * SLOT_DW)   // 5664 dwords = 22656 B
#define NTASK 336               // 6 rows x 4 quads x 14 px-groups

typedef __attribute__((ext_vector_type(8))) short short8v;
typedef __attribute__((ext_vector_type(4))) float float4v;
typedef __attribute__((ext_vector_type(4))) unsigned int uint4v;

__device__ __forceinline__ unsigned bf16rne(float f) {
    unsigned u = __float_as_uint(f);
    return (u + 0x7FFFu + ((u >> 16) & 1u)) >> 16;
}

#define MFMA __builtin_amdgcn_mfma_f32_16x16x32_bf16

// w[g][j][c][tap] f32 -> wt[g][tap][j][c] bf16.
__global__ __launch_bounds__(256)
void transpose_w(const float* __restrict__ w, unsigned short* __restrict__ wt) {
    const int idx = blockIdx.x * 256 + threadIdx.x;   // (g,j,c), 16384 total
    const float* src = w + (size_t)idx * 9;
    const int g = idx >> 11, jc = idx & 2047;
    #pragma unroll
    for (int t = 0; t < 9; ++t)
        wt[(g * 9 + t) * 2048 + jc] = (unsigned short)bf16rne(src[t]);
}

__global__ __launch_bounds__(256, 4)
void gconv_mfma(const float* __restrict__ x,
                const unsigned short* __restrict__ wt,
                const float* __restrict__ bias,
                const int* __restrict__ arr,
                float* __restrict__ out) {
    __shared__ __align__(16) unsigned int smw[BUF_DW];

    const int tid   = threadIdx.x;
    const int chunk = blockIdx.x;      // 0..13 -> output rows [chunk*4, chunk*4+4)
    const int b     = blockIdx.y;
    const int g     = blockIdx.z;
    const int lane  = tid & 63;
    const int wid   = tid >> 6;
    const int n     = lane & 15;       // pixel-in-tile / j-in-tile
    const int kq    = lane >> 4;       // channel-quad (channels kq*8..kq*8+7)
    const int jt0   = (wid & 1) * 2;   // j-half: j-tiles {jt0, jt0+1}
    const int ph    = wid >> 1;        // row-half: chunk rows {2ph, 2ph+1}
    const int rbase = chunk * 4;

    // ---- A-fragments: 18 coalesced 16-B loads from pre-transposed weights ----
    short8v A[2][9];
    #pragma unroll
    for (int jj = 0; jj < 2; ++jj) {
        const unsigned short* wl =
            wt + (size_t)(g * 9) * 2048 + ((jt0 + jj) * 16 + n) * CPER + kq * 8;
        #pragma unroll
        for (int t = 0; t < 9; ++t)
            A[jj][t] = *(const short8v*)(wl + t * 2048);
    }
    float4v binit[2];
    #pragma unroll
    for (int jj = 0; jj < 2; ++jj)
        #pragma unroll
        for (int i = 0; i < 4; ++i)
            binit[jj][i] = bias[g * NJ + (jt0 + jj) * 16 + kq * 4 + i];

    // ---- zero halo pixels (px 0 and 57 of every plane): 48 b128 writes ----
    if (tid < 48) {
        int lr = tid >> 3, rm = tid & 7;
        int q = rm >> 1, px = (rm & 1) ? 57 : 0;
        uint4v z = {0u, 0u, 0u, 0u};
        *(uint4v*)(smw + lr * SLOT_DW + q * PLANE_DW + px * 4) = z;
    }

    // ---- stage 6 input rows (rbase-1 .. rbase+4), task = (quad, px-group) ----
    const float* xb = x + (size_t)b * (CIN * HW);
    const int* ag = arr + g * CPER;
    auto stage = [&](int t) {
        int q = t & 3, s = t >> 2;
        int p4 = s % 14, lr = s / 14;
        int irow = rbase - 1 + lr;
        bool v = (unsigned)irow < NH;
        const float* src = xb + irow * NW + 4 * p4;
        float4v vv[8];
        #pragma unroll
        for (int j = 0; j < 8; ++j) {
            float4v t0 = {0.f, 0.f, 0.f, 0.f};
            if (v) t0 = *(const float4v*)(src + ag[8 * q + j] * HW);
            vv[j] = t0;
        }
        unsigned int* d = smw + lr * SLOT_DW + q * PLANE_DW + (1 + 4 * p4) * 4;
        #pragma unroll
        for (int i = 0; i < 4; ++i) {
            uint4v val;
            #pragma unroll
            for (int dd = 0; dd < 4; ++dd)
                val[dd] = bf16rne(vv[2 * dd][i]) | (bf16rne(vv[2 * dd + 1][i]) << 16);
            *(uint4v*)(d + 4 * i) = val;
        }
    };
    stage(tid);
    if (tid < NTASK - 256) stage(tid + 256);
    __syncthreads();

    // ---- compute: wave (jt0, ph) does 7 tiles (chunk rows 2ph..2ph+1) ----
    const int ob0 = ((b * (NG * NJ) + g * NJ + jt0 * 16 + kq * 4) * NH + rbase) * NW;
    const int ob1 = ob0 + 16 * HW;     // second j-tile (+16 output channels)
    int rl = 2 * ph, col = n;
    #pragma unroll
    for (int tp = 0; tp < 3; ++tp) {
        const int rlA = rl, colA = col;
        col += 16; if (col >= NW) { col -= NW; ++rl; }
        const int rlB = rl, colB = col;
        col += 16; if (col >= NW) { col -= NW; ++rl; }
        const unsigned int* pA = smw + rlA * SLOT_DW + kq * PLANE_DW + colA * 4;
        const unsigned int* pB = smw + rlB * SLOT_DW + kq * PLANE_DW + colB * 4;
        float4v a00 = binit[0], a01 = binit[1];
        float4v a10 = binit[0], a11 = binit[1];
        #pragma unroll
        for (int kh = 0; kh < 3; ++kh)
            #pragma unroll
            for (int kw = 0; kw < 3; ++kw) {
                short8v x0 = *(const short8v*)(pA + kh * SLOT_DW + kw * 4);
                short8v y0 = *(const short8v*)(pB + kh * SLOT_DW + kw * 4);
                a00 = MFMA(A[0][kh * 3 + kw], x0, a00, 0, 0, 0);
                a01 = MFMA(A[1][kh * 3 + kw], x0, a01, 0, 0, 0);
                a10 = MFMA(A[0][kh * 3 + kw], y0, a10, 0, 0, 0);
                a11 = MFMA(A[1][kh * 3 + kw], y0, a11, 0, 0, 0);
            }
        const int oA = rlA * NW + colA;
        const int oB = rlB * NW + colB;
        #pragma unroll
        for (int i = 0; i < 4; ++i) {
            out[ob0 + oA + i * HW] = a00[i];
            out[ob1 + oA + i * HW] = a01[i];
            out[ob0 + oB + i * HW] = a10[i];
            out[ob1 + oB + i * HW] = a11[i];
        }
    }
    // tile 6 (single)
    const unsigned int* pA = smw + rl * SLOT_DW + kq * PLANE_DW + col * 4;
    float4v a00 = binit[0], a01 = binit[1];
    #pragma unroll
    for (int kh = 0; kh < 3; ++kh)
        #pragma unroll
        for (int kw = 0; kw < 3; ++kw) {
            short8v x0 = *(const short8v*)(pA + kh * SLOT_DW + kw * 4);
            a00 = MFMA(A[0][kh * 3 + kw], x0, a00, 0, 0, 0);
            a01 = MFMA(A[1][kh * 3 + kw], x0, a01, 0, 0, 0);
        }
    const int oA = rl * NW + col;
    #pragma unroll
    for (int i = 0; i < 4; ++i) {
        out[ob0 + oA + i * HW] = a00[i];
        out[ob1 + oA + i * HW] = a01[i];
    }
}

extern "C" void kernel_launch(void* const* d_in, const int* in_sizes, int n_in,
                              void* d_out, int out_size, void* d_ws, size_t ws_size,
                              hipStream_t stream) {
    const float* x    = (const float*)d_in[0];
    const float* wght = (const float*)d_in[1];
    const float* bias = (const float*)d_in[2];
    const int*   arr  = (const int*)d_in[3];
    float* out = (float*)d_out;
    unsigned short* wtp = (unsigned short*)d_ws;   // needs 294912 B

    transpose_w<<<dim3(64), 256, 0, stream>>>(wght, wtp);
    dim3 grid(14, NB, NG);   // 14 row-chunks x batch x group = 1792 blocks
    gconv_mfma<<<grid, 256, 0, stream>>>(x, wtp, bias, arr, out);
}

// Round 9
// 199.553 us; speedup vs baseline: 1.0059x; 1.0059x over previous
//
#include <hip/hip_runtime.h>

// GroupedConv2d via bf16 MFMA implicit GEMM — global weights + j-reuse-2,
// spill-free prologue ordering.
// G=8 groups x 32 gathered channels -> J=64, 3x3 pad=1.
// x[16,256,56,56] fp32 -> out[16,512,56,56] fp32.
//
// (1) transpose_w: w[g][j][c][t] f32 -> wt[g][t][j][c] bf16 (295 KB in d_ws).
// (2) main: block = (g, b, chunk of 4 output rows). 4 waves = (j-half) x
// (row-half): each wave holds TWO j-tiles' A-fragments (A[2][9], 72 VGPR)
// and computes 7 pixel-tiles x 2 jt; every LDS B-fragment feeds 2 MFMAs
// (252 ds_read_b128/block, conflicts 4.1M->2.1M verified in round 8).
//
// ROUND-8 LESSON: loading A BEFORE pixel staging made A (72) + staging
// vv[8] (32) simultaneously live -> >128 VGPR cap -> scratch spills
// (+41 MB fetch, +63 MB write, +30 us). THIS version stages pixels FIRST,
// then a sched_barrier(0) fence, THEN loads A+bias right before the
// barrier (L2 latency hides under the barrier wait). Peak pressure
// max(staging ~60, compute ~100) < 128 -> no spill.
//
// LDS = quad-plane pixel buffer: [row 0..5][kq][px 0..58], 16 B/pixel-quad;
// px p holds input col p-1 (px 0/57 = zero halo). Staging writes and
// compute reads both sweep the 8 quad-banks -> conflict-free.
// 22.6 KB LDS, single __syncthreads, grid 1792.

#define NG 8
#define CPER 32
#define CIN 256
#define NJ 64
#define NB 16
#define NH 56
#define NW 56
#define HW (NH * NW)
#define PLANE_DW 236            // 59 px * 4 dwords (16 B per pixel-quad)
#define SLOT_DW 944             // 4 planes per row-slot
#define NSLOT 6
#define BUF_DW (NSLOT * SLOT_DW)   // 5664 dwords = 22656 B
#define NTASK 336               // 6 rows x 4 quads x 14 px-groups

typedef __attribute__((ext_vector_type(8))) short short8v;
typedef __attribute__((ext_vector_type(4))) float float4v;
typedef __attribute__((ext_vector_type(4))) unsigned int uint4v;

__device__ __forceinline__ unsigned bf16rne(float f) {
    unsigned u = __float_as_uint(f);
    return (u + 0x7FFFu + ((u >> 16) & 1u)) >> 16;
}

#define MFMA __builtin_amdgcn_mfma_f32_16x16x32_bf16

// w[g][j][c][tap] f32 -> wt[g][tap][j][c] bf16.
__global__ __launch_bounds__(256)
void transpose_w(const float* __restrict__ w, unsigned short* __restrict__ wt) {
    const int idx = blockIdx.x * 256 + threadIdx.x;   // (g,j,c), 16384 total
    const float* src = w + (size_t)idx * 9;
    const int g = idx >> 11, jc = idx & 2047;
    #pragma unroll
    for (int t = 0; t < 9; ++t)
        wt[(g * 9 + t) * 2048 + jc] = (unsigned short)bf16rne(src[t]);
}

__global__ __launch_bounds__(256, 4)
void gconv_mfma(const float* __restrict__ x,
                const unsigned short* __restrict__ wt,
                const float* __restrict__ bias,
                const int* __restrict__ arr,
                float* __restrict__ out) {
    __shared__ __align__(16) unsigned int smw[BUF_DW];

    const int tid   = threadIdx.x;
    const int chunk = blockIdx.x;      // 0..13 -> output rows [chunk*4, chunk*4+4)
    const int b     = blockIdx.y;
    const int g     = blockIdx.z;
    const int lane  = tid & 63;
    const int wid   = tid >> 6;
    const int n     = lane & 15;       // pixel-in-tile / j-in-tile
    const int kq    = lane >> 4;       // channel-quad (channels kq*8..kq*8+7)
    const int jt0   = (wid & 1) * 2;   // j-half: j-tiles {jt0, jt0+1}
    const int ph    = wid >> 1;        // row-half: chunk rows {2ph, 2ph+1}
    const int rbase = chunk * 4;

    // ---- zero halo pixels (px 0 and 57 of every plane): 48 b128 writes ----
    if (tid < 48) {
        int lr = tid >> 3, rm = tid & 7;
        int q = rm >> 1, px = (rm & 1) ? 57 : 0;
        uint4v z = {0u, 0u, 0u, 0u};
        *(uint4v*)(smw + lr * SLOT_DW + q * PLANE_DW + px * 4) = z;
    }

    // ---- stage 6 input rows (rbase-1 .. rbase+4), task = (quad, px-group) ----
    const float* xb = x + (size_t)b * (CIN * HW);
    const int* ag = arr + g * CPER;
    auto stage = [&](int t) {
        int q = t & 3, s = t >> 2;
        int p4 = s % 14, lr = s / 14;
        int irow = rbase - 1 + lr;
        bool v = (unsigned)irow < NH;
        const float* src = xb + irow * NW + 4 * p4;
        float4v vv[8];
        #pragma unroll
        for (int j = 0; j < 8; ++j) {
            float4v t0 = {0.f, 0.f, 0.f, 0.f};
            if (v) t0 = *(const float4v*)(src + ag[8 * q + j] * HW);
            vv[j] = t0;
        }
        unsigned int* d = smw + lr * SLOT_DW + q * PLANE_DW + (1 + 4 * p4) * 4;
        #pragma unroll
        for (int i = 0; i < 4; ++i) {
            uint4v val;
            #pragma unroll
            for (int dd = 0; dd < 4; ++dd)
                val[dd] = bf16rne(vv[2 * dd][i]) | (bf16rne(vv[2 * dd + 1][i]) << 16);
            *(uint4v*)(d + 4 * i) = val;
        }
    };
    stage(tid);
    if (tid < NTASK - 256) stage(tid + 256);

    // ---- fence: keep A-loads BELOW staging (round-8 spill was A live
    //      across the vv[8] staging window) ----
    __builtin_amdgcn_sched_barrier(0);

    // ---- A-fragments: 18 coalesced 16-B loads from pre-transposed weights;
    //      issued just before the barrier so L2 latency hides under it ----
    short8v A[2][9];
    #pragma unroll
    for (int jj = 0; jj < 2; ++jj) {
        const unsigned short* wl =
            wt + (size_t)(g * 9) * 2048 + ((jt0 + jj) * 16 + n) * CPER + kq * 8;
        #pragma unroll
        for (int t = 0; t < 9; ++t)
            A[jj][t] = *(const short8v*)(wl + t * 2048);
    }
    float4v binit[2];
    #pragma unroll
    for (int jj = 0; jj < 2; ++jj)
        #pragma unroll
        for (int i = 0; i < 4; ++i)
            binit[jj][i] = bias[g * NJ + (jt0 + jj) * 16 + kq * 4 + i];

    __syncthreads();

    // ---- compute: wave (jt0, ph) does 7 tiles (chunk rows 2ph..2ph+1) ----
    const int ob0 = ((b * (NG * NJ) + g * NJ + jt0 * 16 + kq * 4) * NH + rbase) * NW;
    const int ob1 = ob0 + 16 * HW;     // second j-tile (+16 output channels)
    int rl = 2 * ph, col = n;
    #pragma unroll
    for (int tp = 0; tp < 3; ++tp) {
        const int rlA = rl, colA = col;
        col += 16; if (col >= NW) { col -= NW; ++rl; }
        const int rlB = rl, colB = col;
        col += 16; if (col >= NW) { col -= NW; ++rl; }
        const unsigned int* pA = smw + rlA * SLOT_DW + kq * PLANE_DW + colA * 4;
        const unsigned int* pB = smw + rlB * SLOT_DW + kq * PLANE_DW + colB * 4;
        float4v a00 = binit[0], a01 = binit[1];
        float4v a10 = binit[0], a11 = binit[1];
        #pragma unroll
        for (int kh = 0; kh < 3; ++kh)
            #pragma unroll
            for (int kw = 0; kw < 3; ++kw) {
                short8v x0 = *(const short8v*)(pA + kh * SLOT_DW + kw * 4);
                short8v y0 = *(const short8v*)(pB + kh * SLOT_DW + kw * 4);
                a00 = MFMA(A[0][kh * 3 + kw], x0, a00, 0, 0, 0);
                a01 = MFMA(A[1][kh * 3 + kw], x0, a01, 0, 0, 0);
                a10 = MFMA(A[0][kh * 3 + kw], y0, a10, 0, 0, 0);
                a11 = MFMA(A[1][kh * 3 + kw], y0, a11, 0, 0, 0);
            }
        const int oA = rlA * NW + colA;
        const int oB = rlB * NW + colB;
        #pragma unroll
        for (int i = 0; i < 4; ++i) {
            out[ob0 + oA + i * HW] = a00[i];
            out[ob1 + oA + i * HW] = a01[i];
            out[ob0 + oB + i * HW] = a10[i];
            out[ob1 + oB + i * HW] = a11[i];
        }
    }
    // tile 6 (single)
    const unsigned int* pA = smw + rl * SLOT_DW + kq * PLANE_DW + col * 4;
    float4v a00 = binit[0], a01 = binit[1];
    #pragma unroll
    for (int kh = 0; kh < 3; ++kh)
        #pragma unroll
        for (int kw = 0; kw < 3; ++kw) {
            short8v x0 = *(const short8v*)(pA + kh * SLOT_DW + kw * 4);
            a00 = MFMA(A[0][kh * 3 + kw], x0, a00, 0, 0, 0);
            a01 = MFMA(A[1][kh * 3 + kw], x0, a01, 0, 0, 0);
        }
    const int oA = rl * NW + col;
    #pragma unroll
    for (int i = 0; i < 4; ++i) {
        out[ob0 + oA + i * HW] = a00[i];
        out[ob1 + oA + i * HW] = a01[i];
    }
}

extern "C" void kernel_launch(void* const* d_in, const int* in_sizes, int n_in,
                              void* d_out, int out_size, void* d_ws, size_t ws_size,
                              hipStream_t stream) {
    const float* x    = (const float*)d_in[0];
    const float* wght = (const float*)d_in[1];
    const float* bias = (const float*)d_in[2];
    const int*   arr  = (const int*)d_in[3];
    float* out = (float*)d_out;
    unsigned short* wtp = (unsigned short*)d_ws;   // needs 294912 B

    transpose_w<<<dim3(64), 256, 0, stream>>>(wght, wtp);
    dim3 grid(14, NB, NG);   // 14 row-chunks x batch x group = 1792 blocks
    gconv_mfma<<<grid, 256, 0, stream>>>(x, wtp, bias, arr, out);
}

// Round 10
// 183.101 us; speedup vs baseline: 1.0963x; 1.0899x over previous
//
#include <hip/hip_runtime.h>

// GroupedConv2d via bf16 MFMA implicit GEMM — global weights + j-reuse-2,
// occupancy floor relaxed to stop the allocator spilling A.
// G=8 groups x 32 gathered channels -> J=64, 3x3 pad=1.
// x[16,256,56,56] fp32 -> out[16,512,56,56] fp32.
//
// (1) transpose_w: w[g][j][c][t] f32 -> wt[g][t][j][c] bf16 (295 KB in d_ws).
// (2) main: block = (g, b, chunk of 4 output rows). 4 waves = (j-half) x
// (row-half): each wave holds TWO j-tiles' A-fragments (A[2][9], 72 VGPR)
// and computes 7 pixel-tiles x 2 jt; every LDS B-fragment feeds 2 MFMAs
// (252 ds_read_b128/block; conflicts 4.1M->2.1M verified in round 8).
//
// ROUND-8/9 LESSON: with __launch_bounds__(256,4) the allocator pinned the
// kernel at exactly 64 VGPR (the 8-waves/SIMD boundary) and spilled the
// A-fragments to scratch: +44 MB fetch, +78 MB write, +30 us — regardless
// of prologue ordering (round 9 reorder: no change). Fix: launch_bounds
// (256,2) relaxes the floor so ~110-130 VGPR allocates spill-free (round-0
// baseline with (256,2) got 104 VGPR spill-free on this harness).
// Expect 3-4 blocks/CU (VGPR-bound; LDS 22.6 KB would allow 7).
//
// LDS = quad-plane pixel buffer: [row 0..5][kq][px 0..58], 16 B/pixel-quad;
// px p holds input col p-1 (px 0/57 = zero halo). Staging writes and
// compute reads both sweep the 8 quad-banks -> conflict-free.
// 22.6 KB LDS, single __syncthreads, grid 1792.

#define NG 8
#define CPER 32
#define CIN 256
#define NJ 64
#define NB 16
#define NH 56
#define NW 56
#define HW (NH * NW)
#define PLANE_DW 236            // 59 px * 4 dwords (16 B per pixel-quad)
#define SLOT_DW 944             // 4 planes per row-slot
#define NSLOT 6
#define BUF_DW (NSLOT * SLOT_DW)   // 5664 dwords = 22656 B
#define NTASK 336               // 6 rows x 4 quads x 14 px-groups

typedef __attribute__((ext_vector_type(8))) short short8v;
typedef __attribute__((ext_vector_type(4))) float float4v;
typedef __attribute__((ext_vector_type(4))) unsigned int uint4v;

__device__ __forceinline__ unsigned bf16rne(float f) {
    unsigned u = __float_as_uint(f);
    return (u + 0x7FFFu + ((u >> 16) & 1u)) >> 16;
}

#define MFMA __builtin_amdgcn_mfma_f32_16x16x32_bf16

// w[g][j][c][tap] f32 -> wt[g][tap][j][c] bf16.
__global__ __launch_bounds__(256)
void transpose_w(const float* __restrict__ w, unsigned short* __restrict__ wt) {
    const int idx = blockIdx.x * 256 + threadIdx.x;   // (g,j,c), 16384 total
    const float* src = w + (size_t)idx * 9;
    const int g = idx >> 11, jc = idx & 2047;
    #pragma unroll
    for (int t = 0; t < 9; ++t)
        wt[(g * 9 + t) * 2048 + jc] = (unsigned short)bf16rne(src[t]);
}

__global__ __launch_bounds__(256, 2)
void gconv_mfma(const float* __restrict__ x,
                const unsigned short* __restrict__ wt,
                const float* __restrict__ bias,
                const int* __restrict__ arr,
                float* __restrict__ out) {
    __shared__ __align__(16) unsigned int smw[BUF_DW];

    const int tid   = threadIdx.x;
    const int chunk = blockIdx.x;      // 0..13 -> output rows [chunk*4, chunk*4+4)
    const int b     = blockIdx.y;
    const int g     = blockIdx.z;
    const int lane  = tid & 63;
    const int wid   = tid >> 6;
    const int n     = lane & 15;       // pixel-in-tile / j-in-tile
    const int kq    = lane >> 4;       // channel-quad (channels kq*8..kq*8+7)
    const int jt0   = (wid & 1) * 2;   // j-half: j-tiles {jt0, jt0+1}
    const int ph    = wid >> 1;        // row-half: chunk rows {2ph, 2ph+1}
    const int rbase = chunk * 4;

    // ---- zero halo pixels (px 0 and 57 of every plane): 48 b128 writes ----
    if (tid < 48) {
        int lr = tid >> 3, rm = tid & 7;
        int q = rm >> 1, px = (rm & 1) ? 57 : 0;
        uint4v z = {0u, 0u, 0u, 0u};
        *(uint4v*)(smw + lr * SLOT_DW + q * PLANE_DW + px * 4) = z;
    }

    // ---- stage 6 input rows (rbase-1 .. rbase+4), task = (quad, px-group) ----
    const float* xb = x + (size_t)b * (CIN * HW);
    const int* ag = arr + g * CPER;
    auto stage = [&](int t) {
        int q = t & 3, s = t >> 2;
        int p4 = s % 14, lr = s / 14;
        int irow = rbase - 1 + lr;
        bool v = (unsigned)irow < NH;
        const float* src = xb + irow * NW + 4 * p4;
        float4v vv[8];
        #pragma unroll
        for (int j = 0; j < 8; ++j) {
            float4v t0 = {0.f, 0.f, 0.f, 0.f};
            if (v) t0 = *(const float4v*)(src + ag[8 * q + j] * HW);
            vv[j] = t0;
        }
        unsigned int* d = smw + lr * SLOT_DW + q * PLANE_DW + (1 + 4 * p4) * 4;
        #pragma unroll
        for (int i = 0; i < 4; ++i) {
            uint4v val;
            #pragma unroll
            for (int dd = 0; dd < 4; ++dd)
                val[dd] = bf16rne(vv[2 * dd][i]) | (bf16rne(vv[2 * dd + 1][i]) << 16);
            *(uint4v*)(d + 4 * i) = val;
        }
    };
    stage(tid);
    if (tid < NTASK - 256) stage(tid + 256);

    // ---- fence: keep A-loads below staging (limit simultaneous liveness) ----
    __builtin_amdgcn_sched_barrier(0);

    // ---- A-fragments: 18 coalesced 16-B loads from pre-transposed weights;
    //      issued just before the barrier so L2 latency hides under it ----
    short8v A[2][9];
    #pragma unroll
    for (int jj = 0; jj < 2; ++jj) {
        const unsigned short* wl =
            wt + (size_t)(g * 9) * 2048 + ((jt0 + jj) * 16 + n) * CPER + kq * 8;
        #pragma unroll
        for (int t = 0; t < 9; ++t)
            A[jj][t] = *(const short8v*)(wl + t * 2048);
    }
    float4v binit[2];
    #pragma unroll
    for (int jj = 0; jj < 2; ++jj)
        #pragma unroll
        for (int i = 0; i < 4; ++i)
            binit[jj][i] = bias[g * NJ + (jt0 + jj) * 16 + kq * 4 + i];

    __syncthreads();

    // ---- compute: wave (jt0, ph) does 7 tiles (chunk rows 2ph..2ph+1) ----
    const int ob0 = ((b * (NG * NJ) + g * NJ + jt0 * 16 + kq * 4) * NH + rbase) * NW;
    const int ob1 = ob0 + 16 * HW;     // second j-tile (+16 output channels)
    int rl = 2 * ph, col = n;
    #pragma unroll
    for (int tp = 0; tp < 3; ++tp) {
        const int rlA = rl, colA = col;
        col += 16; if (col >= NW) { col -= NW; ++rl; }
        const int rlB = rl, colB = col;
        col += 16; if (col >= NW) { col -= NW; ++rl; }
        const unsigned int* pA = smw + rlA * SLOT_DW + kq * PLANE_DW + colA * 4;
        const unsigned int* pB = smw + rlB * SLOT_DW + kq * PLANE_DW + colB * 4;
        float4v a00 = binit[0], a01 = binit[1];
        float4v a10 = binit[0], a11 = binit[1];
        #pragma unroll
        for (int kh = 0; kh < 3; ++kh)
            #pragma unroll
            for (int kw = 0; kw < 3; ++kw) {
                short8v x0 = *(const short8v*)(pA + kh * SLOT_DW + kw * 4);
                short8v y0 = *(const short8v*)(pB + kh * SLOT_DW + kw * 4);
                a00 = MFMA(A[0][kh * 3 + kw], x0, a00, 0, 0, 0);
                a01 = MFMA(A[1][kh * 3 + kw], x0, a01, 0, 0, 0);
                a10 = MFMA(A[0][kh * 3 + kw], y0, a10, 0, 0, 0);
                a11 = MFMA(A[1][kh * 3 + kw], y0, a11, 0, 0, 0);
            }
        const int oA = rlA * NW + colA;
        const int oB = rlB * NW + colB;
        #pragma unroll
        for (int i = 0; i < 4; ++i) {
            out[ob0 + oA + i * HW] = a00[i];
            out[ob1 + oA + i * HW] = a01[i];
            out[ob0 + oB + i * HW] = a10[i];
            out[ob1 + oB + i * HW] = a11[i];
        }
    }
    // tile 6 (single)
    const unsigned int* pA = smw + rl * SLOT_DW + kq * PLANE_DW + col * 4;
    float4v a00 = binit[0], a01 = binit[1];
    #pragma unroll
    for (int kh = 0; kh < 3; ++kh)
        #pragma unroll
        for (int kw = 0; kw < 3; ++kw) {
            short8v x0 = *(const short8v*)(pA + kh * SLOT_DW + kw * 4);
            a00 = MFMA(A[0][kh * 3 + kw], x0, a00, 0, 0, 0);
            a01 = MFMA(A[1][kh * 3 + kw], x0, a01, 0, 0, 0);
        }
    const int oA = rl * NW + col;
    #pragma unroll
    for (int i = 0; i < 4; ++i) {
        out[ob0 + oA + i * HW] = a00[i];
        out[ob1 + oA + i * HW] = a01[i];
    }
}

extern "C" void kernel_launch(void* const* d_in, const int* in_sizes, int n_in,
                              void* d_out, int out_size, void* d_ws, size_t ws_size,
                              hipStream_t stream) {
    const float* x    = (const float*)d_in[0];
    const float* wght = (const float*)d_in[1];
    const float* bias = (const float*)d_in[2];
    const int*   arr  = (const int*)d_in[3];
    float* out = (float*)d_out;
    unsigned short* wtp = (unsigned short*)d_ws;   // needs 294912 B

    transpose_w<<<dim3(64), 256, 0, stream>>>(wght, wtp);
    dim3 grid(14, NB, NG);   // 14 row-chunks x batch x group = 1792 blocks
    gconv_mfma<<<grid, 256, 0, stream>>>(x, wtp, bias, arr, out);
}